// Round 6
// baseline (296.486 us; speedup 1.0000x reference)
//
#include <hip/hip_runtime.h>
#include <hip/hip_fp16.h>

typedef _Float16 f16x8 __attribute__((ext_vector_type(8)));
typedef float    f32x4 __attribute__((ext_vector_type(4)));

#define BM 64     // 64-row block tile -> 76.8 KB LDS -> 2 blocks/CU, 4 waves/SIMD

// layer geometry (h=0 => only first IN rows of each weight matter; the
// padded K range includes a bias row at k==IN carrying 1.0 in activations)
#define IN0 74
#define H0  269
#define H1  179
#define H2  64
#define KS0 3     // ceil((IN0+1)/32)
#define KS1 9     // ceil((H0+1)/32)
#define KS2 6     // ceil((H1+1)/32)
#define NP0 272
#define NP1 192
#define NP2 64
#define PX  104   // LDS row pitches (halfs): chosen so b128 reads are <=2-way
#define PH0 296
#define PH1 200

__device__ __forceinline__ float fsigm(float z) {
  return __builtin_amdgcn_rcpf(1.f + __expf(-z));
}
__device__ __forceinline__ float ftanh(float v) {
  return 1.f - 2.f * __builtin_amdgcn_rcpf(1.f + __expf(2.f * v));
}

// One CfC layer for this block's 64 rows. 8 waves iterate flat work-units
// u = (tile t = u/G, row-group u%G of S*16 rows). Per unit:
//   preload B(ta,tb) -> MFMA sweep -> preload B(ff1,ff2) (loads in flight)
//   -> ti = sigmoid(tb-ta) (trans hides load latency) -> MFMA sweep
//   -> o = th1 + ti*(th2-th1). Bias arrives via the k==IN one-hot column.
// Weights are packed fragment-major: chunk c=(t*KS+ks)*4+m, lane*8 halfs,
// so every B load is one coalesced global_load_dwordx4.
template<int KS, int NP, int HID, int IPITCH, int OPITCH, bool LAST, int S, int G>
__device__ __forceinline__ void layer_run(
    const _Float16* in_lds, _Float16* out_lds, float* out_g,
    const _Float16* __restrict__ wt, int lane, int wid)
{
  constexpr int NT = NP / 16;
  const int l15 = lane & 15;
  const int lg  = lane >> 4;
  for (int u = wid; u < NT * G; u += 8) {
    const int t     = u / G;
    const int mbase = (u % G) * (S * 16);
    const int n0 = t * 16 + l15;
    const _Float16* a_base = in_lds + (mbase + l15) * IPITCH + lg * 8;
    const _Float16* wtt = wt + (size_t)(t * KS * 4) * 512 + lane * 8;

    // ---- sweep 1: mats 2,3 = ta, tb ----
    f16x8 b0[KS], b1[KS];
    #pragma unroll
    for (int ks = 0; ks < KS; ++ks) {
      b0[ks] = *(const f16x8*)(wtt + (size_t)(ks * 4 + 2) * 512);
      b1[ks] = *(const f16x8*)(wtt + (size_t)(ks * 4 + 3) * 512);
    }
    f32x4 acc[2][S] = {};
    #pragma unroll
    for (int ks = 0; ks < KS; ++ks)
      #pragma unroll
      for (int s = 0; s < S; ++s) {
        f16x8 a = *(const f16x8*)(a_base + s * 16 * IPITCH + ks * 32);
        acc[0][s] = __builtin_amdgcn_mfma_f32_16x16x32_f16(a, b0[ks], acc[0][s], 0, 0, 0);
        acc[1][s] = __builtin_amdgcn_mfma_f32_16x16x32_f16(a, b1[ks], acc[1][s], 0, 0, 0);
      }

    // ---- issue sweep-2 B loads, then burn trans cycles on ti ----
    f16x8 c0[KS], c1[KS];
    #pragma unroll
    for (int ks = 0; ks < KS; ++ks) {
      c0[ks] = *(const f16x8*)(wtt + (size_t)(ks * 4    ) * 512);
      c1[ks] = *(const f16x8*)(wtt + (size_t)(ks * 4 + 1) * 512);
    }
    float ti[S][4];
    #pragma unroll
    for (int s = 0; s < S; ++s)
      #pragma unroll
      for (int q = 0; q < 4; ++q)
        ti[s][q] = fsigm(acc[1][s][q] - acc[0][s][q]);

    // ---- sweep 2: mats 0,1 = ff1, ff2 ----
    #pragma unroll
    for (int s = 0; s < S; ++s) {
      f32x4 z = {0.f, 0.f, 0.f, 0.f};
      acc[0][s] = z; acc[1][s] = z;
    }
    #pragma unroll
    for (int ks = 0; ks < KS; ++ks)
      #pragma unroll
      for (int s = 0; s < S; ++s) {
        f16x8 a = *(const f16x8*)(a_base + s * 16 * IPITCH + ks * 32);
        acc[0][s] = __builtin_amdgcn_mfma_f32_16x16x32_f16(a, c0[ks], acc[0][s], 0, 0, 0);
        acc[1][s] = __builtin_amdgcn_mfma_f32_16x16x32_f16(a, c1[ks], acc[1][s], 0, 0, 0);
      }

    #pragma unroll
    for (int s = 0; s < S; ++s) {
      #pragma unroll
      for (int q = 0; q < 4; ++q) {
        float th1 = ftanh(acc[0][s][q]);
        float th2 = ftanh(acc[1][s][q]);
        float o   = th1 + ti[s][q] * (th2 - th1);
        const int row = mbase + s * 16 + lg * 4 + q;
        if (LAST) {
          out_g[row * 64 + n0] = o;        // NP2 == H2, no guard needed
        } else if (n0 < HID) {
          out_lds[row * OPITCH + n0] = (_Float16)o;
        }
      }
    }
  }
}

__global__ __launch_bounds__(512, 4) void cfc_fused(
    const float* __restrict__ x,
    const _Float16* __restrict__ wt0, const _Float16* __restrict__ wt1,
    const _Float16* __restrict__ wt2,
    float* __restrict__ out)
{
  __shared__ __align__(16) _Float16 xs [BM * PX];   // 13312 B
  __shared__ __align__(16) _Float16 h0s[BM * PH0];  // 37888 B
  __shared__ __align__(16) _Float16 h1s[BM * PH1];  // 25600 B  -> 76800 total
  const int tid  = threadIdx.x;
  const int lane = tid & 63;
  const int wid  = tid >> 6;
  const int m0 = blockIdx.x * BM;

  // pad columns: 1.0 at the bias slot k==IN, 0 elsewhere in [IN, KP)
  for (int i = tid; i < BM * 22; i += 512) { int r = i / 22, c = IN0 + i - r * 22; xs [r * PX  + c] = (_Float16)(c == IN0 ? 1.f : 0.f); }
  for (int i = tid; i < BM * 19; i += 512) { int r = i / 19, c = H0  + i - r * 19; h0s[r * PH0 + c] = (_Float16)(c == H0  ? 1.f : 0.f); }
  for (int i = tid; i < BM * 13; i += 512) { int r = i / 13, c = H1  + i - r * 13; h1s[r * PH1 + c] = (_Float16)(c == H1  ? 1.f : 0.f); }

  // stage x (fp32 -> fp16) into LDS, float2-vectorized (74 = 37 float2/row)
  for (int i = tid; i < BM * 37; i += 512) {
    int r = i / 37, p = i - r * 37;
    float2 v = ((const float2*)x)[(size_t)(m0 + r) * 37 + p];
    xs[r * PX + 2 * p]     = (_Float16)v.x;
    xs[r * PX + 2 * p + 1] = (_Float16)v.y;
  }
  __syncthreads();

  layer_run<KS0, NP0, H0, PX,  PH0, false, 4, 1>(xs,  h0s, nullptr, wt0, lane, wid);
  __syncthreads();
  layer_run<KS1, NP1, H1, PH0, PH1, false, 4, 1>(h0s, h1s, nullptr, wt1, lane, wid);
  __syncthreads();
  layer_run<KS2, NP2, H2, PH1, 1,   true,  2, 2>(h1s, nullptr, out + (size_t)m0 * 64,
                                                 wt2, lane, wid);
}

// Pack weights into fragment-major order. One thread per (chunk, lane):
// wt[idx*8 + j] = W_m[k][n] for k = ks*32+(lane>>4)*8+j, n = t*16+(lane&15),
// masked for ff mats; row k==IN carries the bias vector; zero elsewhere.
__global__ void pack_w(const float* __restrict__ wf1, const float* __restrict__ wf2,
                       const float* __restrict__ wta, const float* __restrict__ wtb,
                       const float* __restrict__ bf1, const float* __restrict__ bf2,
                       const float* __restrict__ bta, const float* __restrict__ btb,
                       const int* __restrict__ mask, _Float16* __restrict__ wt,
                       int IN, int HID, int KS, int NT)
{
  int idx = blockIdx.x * 256 + threadIdx.x;
  int total = NT * KS * 4 * 64;
  if (idx >= total) return;
  int lane = idx & 63;
  int c = idx >> 6;          // chunk = (t*KS + ks)*4 + m
  int m = c & 3;
  int tk = c >> 2;
  int ks = tk % KS;
  int t  = tk / KS;
  int n  = t * 16 + (lane & 15);
  int k0 = ks * 32 + (lane >> 4) * 8;
  const float* w = (m == 0) ? wf1 : (m == 1) ? wf2 : (m == 2) ? wta : wtb;
  const float* b = (m == 0) ? bf1 : (m == 1) ? bf2 : (m == 2) ? bta : btb;
  f16x8 v = {};
  if (n < HID) {
    #pragma unroll
    for (int j = 0; j < 8; ++j) {
      int k = k0 + j;
      float f = 0.f;
      if (k < IN) {
        f = w[k * HID + n];
        if (m < 2) f *= (float)mask[k * HID + n];
      } else if (k == IN) {
        f = b[n];
      }
      v[j] = (_Float16)f;
    }
  }
  *(f16x8*)(wt + (size_t)idx * 8) = v;
}

extern "C" void kernel_launch(void* const* d_in, const int* in_sizes, int n_in,
                              void* d_out, int out_size, void* d_ws, size_t ws_size,
                              hipStream_t stream)
{
  const float* x = (const float*)d_in[0];
  const float* Wf1_0 = (const float*)d_in[1];
  const float* bf1_0 = (const float*)d_in[2];
  const float* Wf2_0 = (const float*)d_in[3];
  const float* bf2_0 = (const float*)d_in[4];
  const float* Wta_0 = (const float*)d_in[5];
  const float* bta_0 = (const float*)d_in[6];
  const float* Wtb_0 = (const float*)d_in[7];
  const float* btb_0 = (const float*)d_in[8];
  const int*   msk_0 = (const int*)  d_in[9];
  const float* Wf1_1 = (const float*)d_in[10];
  const float* bf1_1 = (const float*)d_in[11];
  const float* Wf2_1 = (const float*)d_in[12];
  const float* bf2_1 = (const float*)d_in[13];
  const float* Wta_1 = (const float*)d_in[14];
  const float* bta_1 = (const float*)d_in[15];
  const float* Wtb_1 = (const float*)d_in[16];
  const float* btb_1 = (const float*)d_in[17];
  const int*   msk_1 = (const int*)  d_in[18];
  const float* Wf1_2 = (const float*)d_in[19];
  const float* bf1_2 = (const float*)d_in[20];
  const float* Wf2_2 = (const float*)d_in[21];
  const float* bf2_2 = (const float*)d_in[22];
  const float* Wta_2 = (const float*)d_in[23];
  const float* bta_2 = (const float*)d_in[24];
  const float* Wtb_2 = (const float*)d_in[25];
  const float* btb_2 = (const float*)d_in[26];
  const int*   msk_2 = (const int*)  d_in[27];

  char* ws = (char*)d_ws;
  _Float16* wt0 = (_Float16*)(ws + 0);        // 17*3*4*1024 = 208896
  _Float16* wt1 = (_Float16*)(ws + 208896);   // 12*9*4*1024 = 442368
  _Float16* wt2 = (_Float16*)(ws + 651264);   //  4*6*4*1024 =  98304

  pack_w<<<(17 * KS0 * 4 * 64 + 255) / 256, 256, 0, stream>>>(
      Wf1_0, Wf2_0, Wta_0, Wtb_0, bf1_0, bf2_0, bta_0, btb_0, msk_0, wt0, IN0, H0, KS0, 17);
  pack_w<<<(12 * KS1 * 4 * 64 + 255) / 256, 256, 0, stream>>>(
      Wf1_1, Wf2_1, Wta_1, Wtb_1, bf1_1, bf2_1, bta_1, btb_1, msk_1, wt1, H0, H1, KS1, 12);
  pack_w<<<( 4 * KS2 * 4 * 64 + 255) / 256, 256, 0, stream>>>(
      Wf1_2, Wf2_2, Wta_2, Wtb_2, bf1_2, bf2_2, bta_2, btb_2, msk_2, wt2, H1, H2, KS2, 4);

  cfc_fused<<<65536 / BM, 512, 0, stream>>>(x, wt0, wt1, wt2, (float*)d_out);
}

// Round 7
// 270.380 us; speedup vs baseline: 1.0966x; 1.0966x over previous
//
#include <hip/hip_runtime.h>
#include <hip/hip_fp16.h>

typedef _Float16 f16x8 __attribute__((ext_vector_type(8)));
typedef float    f32x4 __attribute__((ext_vector_type(4)));

#define BM 64     // 64-row block tile -> 76.8 KB LDS -> 2 blocks/CU

// layer geometry (h=0 => only first IN rows of each weight matter; the
// padded K range includes a bias row at k==IN carrying 1.0 in activations)
#define IN0 74
#define H0  269
#define H1  179
#define H2  64
#define KS0 3     // ceil((IN0+1)/32)
#define KS1 9     // ceil((H0+1)/32)
#define KS2 6     // ceil((H1+1)/32)
#define NP0 272
#define NP1 192
#define NP2 64
#define PX  104   // LDS row pitches (halfs): chosen so b128 reads are <=2-way
#define PH0 296
#define PH1 200

#define MFMA16(a, b, c) __builtin_amdgcn_mfma_f32_16x16x32_f16(a, b, c, 0, 0, 0)

__device__ __forceinline__ float fsigm(float z) {
  return __builtin_amdgcn_rcpf(1.f + __expf(-z));
}
__device__ __forceinline__ float ftanh(float v) {
  return 1.f - 2.f * __builtin_amdgcn_rcpf(1.f + __expf(2.f * v));
}

// One CfC layer for this block's 64 rows. 8 waves iterate flat work-units
// u = (tile t = u/G, row-group u%G of S*16 rows). Per unit, two K-sweeps
// with a ROLLING 1-ahead B prefetch (live set ~100 regs so the kernel fits
// the 128-reg/wave budget needed for 4 waves/SIMD):
//   sweep ta/tb -> (issue ff B pair) -> ti = sigmoid(tb-ta) -> sweep ff1/ff2
//   -> o = th1 + ti*(th2-th1). Bias arrives via the k==IN one-hot column.
// Weights packed fragment-major: chunk c=(t*KS+ks)*4+m, lane*8 halfs ->
// every B load is one coalesced global_load_dwordx4.
template<int KS, int NP, int HID, int IPITCH, int OPITCH, bool LAST, int S, int G>
__device__ __forceinline__ void layer_run(
    const _Float16* in_lds, _Float16* out_lds, float* out_g,
    const _Float16* __restrict__ wt, int lane, int wid)
{
  constexpr int NT = NP / 16;
  const int l15 = lane & 15;
  const int lg  = lane >> 4;
  for (int u = wid; u < NT * G; u += 8) {
    const int t     = u / G;
    const int mbase = (u % G) * (S * 16);
    const int n0 = t * 16 + l15;
    const _Float16* a_base = in_lds + (mbase + l15) * IPITCH + lg * 8;
    const _Float16* wtt = wt + (size_t)(t * KS * 4) * 512 + lane * 8;

    // ---- sweep 1: mats 2,3 = ta, tb (rolling prefetch) ----
    f32x4 acc[2][S] = {};
    f16x8 p0 = *(const f16x8*)(wtt + 2 * 512);
    f16x8 p1 = *(const f16x8*)(wtt + 3 * 512);
    #pragma unroll
    for (int ks = 0; ks < KS; ++ks) {
      f16x8 nx0, nx1;
      if (ks + 1 < KS) {
        nx0 = *(const f16x8*)(wtt + (size_t)((ks + 1) * 4 + 2) * 512);
        nx1 = *(const f16x8*)(wtt + (size_t)((ks + 1) * 4 + 3) * 512);
      }
      #pragma unroll
      for (int s = 0; s < S; ++s) {
        f16x8 a = *(const f16x8*)(a_base + s * 16 * IPITCH + ks * 32);
        acc[0][s] = MFMA16(a, p0, acc[0][s]);
        acc[1][s] = MFMA16(a, p1, acc[1][s]);
      }
      p0 = nx0; p1 = nx1;
    }

    // ---- issue sweep-2's first B pair, then burn trans cycles on ti ----
    f16x8 q0 = *(const f16x8*)(wtt + 0 * 512);
    f16x8 q1 = *(const f16x8*)(wtt + 1 * 512);
    float ti[S][4];
    #pragma unroll
    for (int s = 0; s < S; ++s)
      #pragma unroll
      for (int q = 0; q < 4; ++q)
        ti[s][q] = fsigm(acc[1][s][q] - acc[0][s][q]);

    // ---- sweep 2: mats 0,1 = ff1, ff2 (rolling prefetch) ----
    #pragma unroll
    for (int s = 0; s < S; ++s) {
      f32x4 z = {0.f, 0.f, 0.f, 0.f};
      acc[0][s] = z; acc[1][s] = z;
    }
    #pragma unroll
    for (int ks = 0; ks < KS; ++ks) {
      f16x8 nx0, nx1;
      if (ks + 1 < KS) {
        nx0 = *(const f16x8*)(wtt + (size_t)((ks + 1) * 4    ) * 512);
        nx1 = *(const f16x8*)(wtt + (size_t)((ks + 1) * 4 + 1) * 512);
      }
      #pragma unroll
      for (int s = 0; s < S; ++s) {
        f16x8 a = *(const f16x8*)(a_base + s * 16 * IPITCH + ks * 32);
        acc[0][s] = MFMA16(a, q0, acc[0][s]);
        acc[1][s] = MFMA16(a, q1, acc[1][s]);
      }
      q0 = nx0; q1 = nx1;
    }

    #pragma unroll
    for (int s = 0; s < S; ++s) {
      #pragma unroll
      for (int q = 0; q < 4; ++q) {
        float th1 = ftanh(acc[0][s][q]);
        float th2 = ftanh(acc[1][s][q]);
        float o   = th1 + ti[s][q] * (th2 - th1);
        const int row = mbase + s * 16 + lg * 4 + q;
        if (LAST) {
          out_g[row * 64 + n0] = o;        // NP2 == H2, no guard needed
        } else if (n0 < HID) {
          out_lds[row * OPITCH + n0] = (_Float16)o;
        }
      }
    }
  }
}

__global__ __launch_bounds__(512, 4) void cfc_fused(
    const float* __restrict__ x,
    const _Float16* __restrict__ wt0, const _Float16* __restrict__ wt1,
    const _Float16* __restrict__ wt2,
    float* __restrict__ out)
{
  __shared__ __align__(16) _Float16 xs [BM * PX];   // 13312 B
  __shared__ __align__(16) _Float16 h0s[BM * PH0];  // 37888 B
  __shared__ __align__(16) _Float16 h1s[BM * PH1];  // 25600 B  -> 76800 total
  const int tid  = threadIdx.x;
  const int lane = tid & 63;
  const int wid  = tid >> 6;
  const int m0 = blockIdx.x * BM;

  // pad columns: 1.0 at the bias slot k==IN, 0 elsewhere in [IN, KP)
  for (int i = tid; i < BM * 22; i += 512) { int r = i / 22, c = IN0 + i - r * 22; xs [r * PX  + c] = (_Float16)(c == IN0 ? 1.f : 0.f); }
  for (int i = tid; i < BM * 19; i += 512) { int r = i / 19, c = H0  + i - r * 19; h0s[r * PH0 + c] = (_Float16)(c == H0  ? 1.f : 0.f); }
  for (int i = tid; i < BM * 13; i += 512) { int r = i / 13, c = H1  + i - r * 13; h1s[r * PH1 + c] = (_Float16)(c == H1  ? 1.f : 0.f); }

  // stage x (fp32 -> fp16) into LDS, float2-vectorized (74 = 37 float2/row)
  for (int i = tid; i < BM * 37; i += 512) {
    int r = i / 37, p = i - r * 37;
    float2 v = ((const float2*)x)[(size_t)(m0 + r) * 37 + p];
    xs[r * PX + 2 * p]     = (_Float16)v.x;
    xs[r * PX + 2 * p + 1] = (_Float16)v.y;
  }
  __syncthreads();

  layer_run<KS0, NP0, H0, PX,  PH0, false, 4, 1>(xs,  h0s, nullptr, wt0, lane, wid);
  __syncthreads();
  layer_run<KS1, NP1, H1, PH0, PH1, false, 4, 1>(h0s, h1s, nullptr, wt1, lane, wid);
  __syncthreads();
  layer_run<KS2, NP2, H2, PH1, 1,   true,  2, 2>(h1s, nullptr, out + (size_t)m0 * 64,
                                                 wt2, lane, wid);
}

// Pack weights into fragment-major order. One thread per (chunk, lane):
// wt[idx*8 + j] = W_m[k][n] for k = ks*32+(lane>>4)*8+j, n = t*16+(lane&15),
// masked for ff mats; row k==IN carries the bias vector; zero elsewhere.
__global__ void pack_w(const float* __restrict__ wf1, const float* __restrict__ wf2,
                       const float* __restrict__ wta, const float* __restrict__ wtb,
                       const float* __restrict__ bf1, const float* __restrict__ bf2,
                       const float* __restrict__ bta, const float* __restrict__ btb,
                       const int* __restrict__ mask, _Float16* __restrict__ wt,
                       int IN, int HID, int KS, int NT)
{
  int idx = blockIdx.x * 256 + threadIdx.x;
  int total = NT * KS * 4 * 64;
  if (idx >= total) return;
  int lane = idx & 63;
  int c = idx >> 6;          // chunk = (t*KS + ks)*4 + m
  int m = c & 3;
  int tk = c >> 2;
  int ks = tk % KS;
  int t  = tk / KS;
  int n  = t * 16 + (lane & 15);
  int k0 = ks * 32 + (lane >> 4) * 8;
  const float* w = (m == 0) ? wf1 : (m == 1) ? wf2 : (m == 2) ? wta : wtb;
  const float* b = (m == 0) ? bf1 : (m == 1) ? bf2 : (m == 2) ? bta : btb;
  f16x8 v = {};
  if (n < HID) {
    #pragma unroll
    for (int j = 0; j < 8; ++j) {
      int k = k0 + j;
      float f = 0.f;
      if (k < IN) {
        f = w[k * HID + n];
        if (m < 2) f *= (float)mask[k * HID + n];
      } else if (k == IN) {
        f = b[n];
      }
      v[j] = (_Float16)f;
    }
  }
  *(f16x8*)(wt + (size_t)idx * 8) = v;
}

extern "C" void kernel_launch(void* const* d_in, const int* in_sizes, int n_in,
                              void* d_out, int out_size, void* d_ws, size_t ws_size,
                              hipStream_t stream)
{
  const float* x = (const float*)d_in[0];
  const float* Wf1_0 = (const float*)d_in[1];
  const float* bf1_0 = (const float*)d_in[2];
  const float* Wf2_0 = (const float*)d_in[3];
  const float* bf2_0 = (const float*)d_in[4];
  const float* Wta_0 = (const float*)d_in[5];
  const float* bta_0 = (const float*)d_in[6];
  const float* Wtb_0 = (const float*)d_in[7];
  const float* btb_0 = (const float*)d_in[8];
  const int*   msk_0 = (const int*)  d_in[9];
  const float* Wf1_1 = (const float*)d_in[10];
  const float* bf1_1 = (const float*)d_in[11];
  const float* Wf2_1 = (const float*)d_in[12];
  const float* bf2_1 = (const float*)d_in[13];
  const float* Wta_1 = (const float*)d_in[14];
  const float* bta_1 = (const float*)d_in[15];
  const float* Wtb_1 = (const float*)d_in[16];
  const float* btb_1 = (const float*)d_in[17];
  const int*   msk_1 = (const int*)  d_in[18];
  const float* Wf1_2 = (const float*)d_in[19];
  const float* bf1_2 = (const float*)d_in[20];
  const float* Wf2_2 = (const float*)d_in[21];
  const float* bf2_2 = (const float*)d_in[22];
  const float* Wta_2 = (const float*)d_in[23];
  const float* bta_2 = (const float*)d_in[24];
  const float* Wtb_2 = (const float*)d_in[25];
  const float* btb_2 = (const float*)d_in[26];
  const int*   msk_2 = (const int*)  d_in[27];

  char* ws = (char*)d_ws;
  _Float16* wt0 = (_Float16*)(ws + 0);        // 17*3*4*1024 = 208896
  _Float16* wt1 = (_Float16*)(ws + 208896);   // 12*9*4*1024 = 442368
  _Float16* wt2 = (_Float16*)(ws + 651264);   //  4*6*4*1024 =  98304

  pack_w<<<(17 * KS0 * 4 * 64 + 255) / 256, 256, 0, stream>>>(
      Wf1_0, Wf2_0, Wta_0, Wtb_0, bf1_0, bf2_0, bta_0, btb_0, msk_0, wt0, IN0, H0, KS0, 17);
  pack_w<<<(12 * KS1 * 4 * 64 + 255) / 256, 256, 0, stream>>>(
      Wf1_1, Wf2_1, Wta_1, Wtb_1, bf1_1, bf2_1, bta_1, btb_1, msk_1, wt1, H0, H1, KS1, 12);
  pack_w<<<( 4 * KS2 * 4 * 64 + 255) / 256, 256, 0, stream>>>(
      Wf1_2, Wf2_2, Wta_2, Wtb_2, bf1_2, bf2_2, bta_2, btb_2, msk_2, wt2, H1, H2, KS2, 4);

  cfc_fused<<<65536 / BM, 512, 0, stream>>>(x, wt0, wt1, wt2, (float*)d_out);
}

// Round 8
// 85.585 us; speedup vs baseline: 3.4642x; 3.1592x over previous
//
#include <hip/hip_runtime.h>
#include <hip/hip_fp16.h>

typedef _Float16 f16x8 __attribute__((ext_vector_type(8)));
typedef float    f32x4 __attribute__((ext_vector_type(4)));

#define BM 64     // 64-row block tile -> 76.8 KB LDS -> 2 blocks/CU

// layer geometry (h=0 => only first IN rows of each weight matter; the
// padded K range includes a bias row at k==IN carrying 1.0 in activations)
#define IN0 74
#define H0  269
#define H1  179
#define H2  64
#define KS0 3     // ceil((IN0+1)/32)
#define KS1 9     // ceil((H0+1)/32)
#define KS2 6     // ceil((H1+1)/32)
#define NP0 272
#define NP1 192
#define NP2 64
#define PX  104   // LDS row pitches (halfs): chosen so b128 reads are <=2-way
#define PH0 296
#define PH1 200

#define MFMA16(a, b, c) __builtin_amdgcn_mfma_f32_16x16x32_f16(a, b, c, 0, 0, 0)

__device__ __forceinline__ float fsigm(float z) {
  return __builtin_amdgcn_rcpf(1.f + __expf(-z));
}
__device__ __forceinline__ float ftanh(float v) {
  return 1.f - 2.f * __builtin_amdgcn_rcpf(1.f + __expf(2.f * v));
}

// One 2-matrix K-sweep with rolling 1-ahead B prefetch. The ks loop is
// FORCIBLY ROLLED (#pragma unroll 1): this is what prevents LLVM from
// hoisting all KS*2 B-loads to the top (the register blowup of rounds
// 3/4/6/7). Per iteration: issue next B pair -> 8 MFMA on current pair.
template<int KS, int S, int IPITCH, int MOFF>
__device__ __forceinline__ void sweep(f32x4 (&acc)[2][S],
    const _Float16* __restrict__ wtt, const _Float16* a_base)
{
  f16x8 b0 = *(const f16x8*)(wtt + (size_t)(MOFF    ) * 512);
  f16x8 b1 = *(const f16x8*)(wtt + (size_t)(MOFF + 1) * 512);
  #pragma unroll 1
  for (int ks = 0; ks < KS - 1; ++ks) {
    f16x8 nb0 = *(const f16x8*)(wtt + (size_t)((ks + 1) * 4 + MOFF    ) * 512);
    f16x8 nb1 = *(const f16x8*)(wtt + (size_t)((ks + 1) * 4 + MOFF + 1) * 512);
    #pragma unroll
    for (int s = 0; s < S; ++s) {
      f16x8 a = *(const f16x8*)(a_base + s * 16 * IPITCH + ks * 32);
      acc[0][s] = MFMA16(a, b0, acc[0][s]);
      acc[1][s] = MFMA16(a, b1, acc[1][s]);
    }
    b0 = nb0; b1 = nb1;
  }
  #pragma unroll
  for (int s = 0; s < S; ++s) {
    f16x8 a = *(const f16x8*)(a_base + s * 16 * IPITCH + (KS - 1) * 32);
    acc[0][s] = MFMA16(a, b0, acc[0][s]);
    acc[1][s] = MFMA16(a, b1, acc[1][s]);
  }
}

// One CfC layer for this block's 64 rows. 8 waves iterate flat work-units
// u = (tile t = u/G, row-group u%G of S*16 rows). Per unit:
//   sweep ta/tb -> issue ff's first B pair -> ti = sigmoid(tb-ta)
//   -> sweep ff1/ff2 -> o = th1 + ti*(th2-th1).
// Bias arrives via the k==IN one-hot column. Weights packed fragment-major:
// chunk c=(t*KS+ks)*4+m, lane*8 halfs -> each B load = 1 coalesced dwordx4.
template<int KS, int NP, int HID, int IPITCH, int OPITCH, bool LAST, int S, int G>
__device__ __forceinline__ void layer_run(
    const _Float16* in_lds, _Float16* out_lds, float* out_g,
    const _Float16* __restrict__ wt, int lane, int wid)
{
  constexpr int NT = NP / 16;
  const int l15 = lane & 15;
  const int lg  = lane >> 4;
  for (int u = wid; u < NT * G; u += 8) {
    const int t     = u / G;
    const int mbase = (u % G) * (S * 16);
    const int ncol  = t * 16 + l15;
    const _Float16* a_base = in_lds + (mbase + l15) * IPITCH + lg * 8;
    const _Float16* wtt = wt + (size_t)(t * KS * 4) * 512 + lane * 8;

    f32x4 acc[2][S] = {};
    sweep<KS, S, IPITCH, 2>(acc, wtt, a_base);          // mats 2,3 = ta,tb

    // issue sweep-2's first B pair, then burn trans cycles on ti
    f16x8 q0 = *(const f16x8*)(wtt);
    f16x8 q1 = *(const f16x8*)(wtt + 512);
    float ti[S][4];
    #pragma unroll
    for (int s = 0; s < S; ++s)
      #pragma unroll
      for (int q = 0; q < 4; ++q)
        ti[s][q] = fsigm(acc[1][s][q] - acc[0][s][q]);

    // sweep 2: mats 0,1 = ff1,ff2 (first pair already in q0/q1)
    #pragma unroll
    for (int s = 0; s < S; ++s) {
      f32x4 z = {0.f, 0.f, 0.f, 0.f};
      acc[0][s] = z; acc[1][s] = z;
    }
    {
      f16x8 b0 = q0, b1 = q1;
      #pragma unroll 1
      for (int ks = 0; ks < KS - 1; ++ks) {
        f16x8 nb0 = *(const f16x8*)(wtt + (size_t)((ks + 1) * 4    ) * 512);
        f16x8 nb1 = *(const f16x8*)(wtt + (size_t)((ks + 1) * 4 + 1) * 512);
        #pragma unroll
        for (int s = 0; s < S; ++s) {
          f16x8 a = *(const f16x8*)(a_base + s * 16 * IPITCH + ks * 32);
          acc[0][s] = MFMA16(a, b0, acc[0][s]);
          acc[1][s] = MFMA16(a, b1, acc[1][s]);
        }
        b0 = nb0; b1 = nb1;
      }
      #pragma unroll
      for (int s = 0; s < S; ++s) {
        f16x8 a = *(const f16x8*)(a_base + s * 16 * IPITCH + (KS - 1) * 32);
        acc[0][s] = MFMA16(a, b0, acc[0][s]);
        acc[1][s] = MFMA16(a, b1, acc[1][s]);
      }
    }

    #pragma unroll
    for (int s = 0; s < S; ++s) {
      #pragma unroll
      for (int q = 0; q < 4; ++q) {
        float th1 = ftanh(acc[0][s][q]);
        float th2 = ftanh(acc[1][s][q]);
        float o   = th1 + ti[s][q] * (th2 - th1);
        const int row = mbase + s * 16 + lg * 4 + q;
        if (LAST) {
          out_g[row * 64 + ncol] = o;      // NP2 == H2, no guard needed
        } else if (ncol < HID) {
          out_lds[row * OPITCH + ncol] = (_Float16)o;
        }
      }
    }
  }
}

__global__ __launch_bounds__(512, 4) void cfc_fused(
    const float* __restrict__ x,
    const _Float16* __restrict__ wt0, const _Float16* __restrict__ wt1,
    const _Float16* __restrict__ wt2,
    float* __restrict__ out)
{
  __shared__ __align__(16) _Float16 xs [BM * PX];   // 13312 B
  __shared__ __align__(16) _Float16 h0s[BM * PH0];  // 37888 B
  __shared__ __align__(16) _Float16 h1s[BM * PH1];  // 25600 B  -> 76800 total
  const int tid  = threadIdx.x;
  const int lane = tid & 63;
  const int wid  = tid >> 6;
  const int m0 = blockIdx.x * BM;

  // pad columns: 1.0 at the bias slot k==IN, 0 elsewhere in [IN, KP)
  for (int i = tid; i < BM * 22; i += 512) { int r = i / 22, c = IN0 + i - r * 22; xs [r * PX  + c] = (_Float16)(c == IN0 ? 1.f : 0.f); }
  for (int i = tid; i < BM * 19; i += 512) { int r = i / 19, c = H0  + i - r * 19; h0s[r * PH0 + c] = (_Float16)(c == H0  ? 1.f : 0.f); }
  for (int i = tid; i < BM * 13; i += 512) { int r = i / 13, c = H1  + i - r * 13; h1s[r * PH1 + c] = (_Float16)(c == H1  ? 1.f : 0.f); }

  // stage x (fp32 -> fp16) into LDS, float2-vectorized (74 = 37 float2/row)
  for (int i = tid; i < BM * 37; i += 512) {
    int r = i / 37, p = i - r * 37;
    float2 v = ((const float2*)x)[(size_t)(m0 + r) * 37 + p];
    xs[r * PX + 2 * p]     = (_Float16)v.x;
    xs[r * PX + 2 * p + 1] = (_Float16)v.y;
  }
  __syncthreads();

  layer_run<KS0, NP0, H0, PX,  PH0, false, 4, 1>(xs,  h0s, nullptr, wt0, lane, wid);
  __syncthreads();
  layer_run<KS1, NP1, H1, PH0, PH1, false, 4, 1>(h0s, h1s, nullptr, wt1, lane, wid);
  __syncthreads();
  layer_run<KS2, NP2, H2, PH1, 1,   true,  2, 2>(h1s, nullptr, out + (size_t)m0 * 64,
                                                 wt2, lane, wid);
}

// Pack weights into fragment-major order. One thread per (chunk, lane):
// wt[idx*8 + j] = W_m[k][n] for k = ks*32+(lane>>4)*8+j, n = t*16+(lane&15),
// masked for ff mats; row k==IN carries the bias vector; zero elsewhere.
__global__ void pack_w(const float* __restrict__ wf1, const float* __restrict__ wf2,
                       const float* __restrict__ wta, const float* __restrict__ wtb,
                       const float* __restrict__ bf1, const float* __restrict__ bf2,
                       const float* __restrict__ bta, const float* __restrict__ btb,
                       const int* __restrict__ mask, _Float16* __restrict__ wt,
                       int IN, int HID, int KS, int NT)
{
  int idx = blockIdx.x * 256 + threadIdx.x;
  int total = NT * KS * 4 * 64;
  if (idx >= total) return;
  int lane = idx & 63;
  int c = idx >> 6;          // chunk = (t*KS + ks)*4 + m
  int m = c & 3;
  int tk = c >> 2;
  int ks = tk % KS;
  int t  = tk / KS;
  int n  = t * 16 + (lane & 15);
  int k0 = ks * 32 + (lane >> 4) * 8;
  const float* w = (m == 0) ? wf1 : (m == 1) ? wf2 : (m == 2) ? wta : wtb;
  const float* b = (m == 0) ? bf1 : (m == 1) ? bf2 : (m == 2) ? bta : btb;
  f16x8 v = {};
  if (n < HID) {
    #pragma unroll
    for (int j = 0; j < 8; ++j) {
      int k = k0 + j;
      float f = 0.f;
      if (k < IN) {
        f = w[k * HID + n];
        if (m < 2) f *= (float)mask[k * HID + n];
      } else if (k == IN) {
        f = b[n];
      }
      v[j] = (_Float16)f;
    }
  }
  *(f16x8*)(wt + (size_t)idx * 8) = v;
}

extern "C" void kernel_launch(void* const* d_in, const int* in_sizes, int n_in,
                              void* d_out, int out_size, void* d_ws, size_t ws_size,
                              hipStream_t stream)
{
  const float* x = (const float*)d_in[0];
  const float* Wf1_0 = (const float*)d_in[1];
  const float* bf1_0 = (const float*)d_in[2];
  const float* Wf2_0 = (const float*)d_in[3];
  const float* bf2_0 = (const float*)d_in[4];
  const float* Wta_0 = (const float*)d_in[5];
  const float* bta_0 = (const float*)d_in[6];
  const float* Wtb_0 = (const float*)d_in[7];
  const float* btb_0 = (const float*)d_in[8];
  const int*   msk_0 = (const int*)  d_in[9];
  const float* Wf1_1 = (const float*)d_in[10];
  const float* bf1_1 = (const float*)d_in[11];
  const float* Wf2_1 = (const float*)d_in[12];
  const float* bf2_1 = (const float*)d_in[13];
  const float* Wta_1 = (const float*)d_in[14];
  const float* bta_1 = (const float*)d_in[15];
  const float* Wtb_1 = (const float*)d_in[16];
  const float* btb_1 = (const float*)d_in[17];
  const int*   msk_1 = (const int*)  d_in[18];
  const float* Wf1_2 = (const float*)d_in[19];
  const float* bf1_2 = (const float*)d_in[20];
  const float* Wf2_2 = (const float*)d_in[21];
  const float* bf2_2 = (const float*)d_in[22];
  const float* Wta_2 = (const float*)d_in[23];
  const float* bta_2 = (const float*)d_in[24];
  const float* Wtb_2 = (const float*)d_in[25];
  const float* btb_2 = (const float*)d_in[26];
  const int*   msk_2 = (const int*)  d_in[27];

  char* ws = (char*)d_ws;
  _Float16* wt0 = (_Float16*)(ws + 0);        // 17*3*4*1024 = 208896
  _Float16* wt1 = (_Float16*)(ws + 208896);   // 12*9*4*1024 = 442368
  _Float16* wt2 = (_Float16*)(ws + 651264);   //  4*6*4*1024 =  98304

  pack_w<<<(17 * KS0 * 4 * 64 + 255) / 256, 256, 0, stream>>>(
      Wf1_0, Wf2_0, Wta_0, Wtb_0, bf1_0, bf2_0, bta_0, btb_0, msk_0, wt0, IN0, H0, KS0, 17);
  pack_w<<<(12 * KS1 * 4 * 64 + 255) / 256, 256, 0, stream>>>(
      Wf1_1, Wf2_1, Wta_1, Wtb_1, bf1_1, bf2_1, bta_1, btb_1, msk_1, wt1, H0, H1, KS1, 12);
  pack_w<<<( 4 * KS2 * 4 * 64 + 255) / 256, 256, 0, stream>>>(
      Wf1_2, Wf2_2, Wta_2, Wtb_2, bf1_2, bf2_2, bta_2, btb_2, msk_2, wt2, H1, H2, KS2, 4);

  cfc_fused<<<65536 / BM, 512, 0, stream>>>(x, wt0, wt1, wt2, (float*)d_out);
}

// Round 9
// 83.422 us; speedup vs baseline: 3.5540x; 1.0259x over previous
//
#include <hip/hip_runtime.h>
#include <hip/hip_fp16.h>

typedef _Float16 f16x8 __attribute__((ext_vector_type(8)));
typedef _Float16 f16x4 __attribute__((ext_vector_type(4)));
typedef _Float16 f16x2 __attribute__((ext_vector_type(2)));
typedef float    f32x4 __attribute__((ext_vector_type(4)));

#define BM 64     // 64-row block tile -> 76.8 KB LDS -> 2 blocks/CU

// layer geometry (h=0 => only first IN rows of each weight matter; the
// padded K range includes a bias row at k==IN carrying 1.0 in activations)
#define IN0 74
#define H0  269
#define H1  179
#define H2  64
#define KS0 3     // ceil((IN0+1)/32)
#define KS1 9     // ceil((H0+1)/32)
#define KS2 6     // ceil((H1+1)/32)
#define NP0 272
#define NP1 192
#define NP2 64
#define PX  104   // LDS row pitches (halfs): odd multiples of 16B -> spread banks
#define PH0 296
#define PH1 200

// SWAPPED operands: weights as the A-matrix, activations as B.
// A/B fragment layouts are symmetric (lane&15 = row/col, (lane>>4)*8+j = k),
// so the SAME packed weight frag and the SAME LDS activation read work; the
// C/D layout becomes col(lane&15)=batch row, row(lg*4+q)=feature -> each
// lane's 4 outputs are 4 CONSECUTIVE features of one batch row.
#define MFMA16(a, b, c) __builtin_amdgcn_mfma_f32_16x16x32_f16(a, b, c, 0, 0, 0)

__device__ __forceinline__ float fsigm(float z) {
  return __builtin_amdgcn_rcpf(1.f + __expf(-z));
}
__device__ __forceinline__ float ftanh(float v) {
  return 1.f - 2.f * __builtin_amdgcn_rcpf(1.f + __expf(2.f * v));
}

// One CfC layer for this block's 64 rows. 8 waves iterate flat work-units
// u = (tile t = u/G, row-group u%G of S*16 rows). Per unit ONE K-sweep with
// all 4 matrices accumulating (acc[4][S] in AGPRs): 1 LDS A-read feeds 4
// MFMAs. Rolling 1-ahead B prefetch in a FORCIBLY ROLLED (#pragma unroll 1)
// ks loop (prevents LLVM hoisting all B loads -> register blowup).
// Epilogue computes o = th1 + sigmoid(tb-ta)*(th2-th1) inline and writes
// packed: f16x4 b64 to LDS (or float4 to global for the last layer).
// Bias arrives via the k==IN one-hot activation column.
template<int KS, int NP, int HID, int IPITCH, int OPITCH, bool LAST, int S, int G>
__device__ __forceinline__ void layer_run(
    const _Float16* in_lds, _Float16* out_lds, float* out_g,
    const _Float16* __restrict__ wt, int lane, int wid)
{
  constexpr int NT = NP / 16;
  const int l15 = lane & 15;
  const int lg  = lane >> 4;
  #pragma unroll 1
  for (int u = wid; u < NT * G; u += 8) {
    const int t     = u / G;
    const int mbase = (u % G) * (S * 16);
    const _Float16* a_base = in_lds + (mbase + l15) * IPITCH + lg * 8;
    const _Float16* wtt = wt + (size_t)(t * KS * 4) * 512 + lane * 8;

    f32x4 acc[4][S] = {};
    f16x8 b0 = *(const f16x8*)(wtt);
    f16x8 b1 = *(const f16x8*)(wtt + 512);
    f16x8 b2 = *(const f16x8*)(wtt + 1024);
    f16x8 b3 = *(const f16x8*)(wtt + 1536);
    #pragma unroll 1
    for (int ks = 0; ks < KS - 1; ++ks) {
      const _Float16* wn = wtt + (size_t)(ks + 1) * 2048;
      f16x8 n0 = *(const f16x8*)(wn);
      f16x8 n1 = *(const f16x8*)(wn + 512);
      f16x8 n2 = *(const f16x8*)(wn + 1024);
      f16x8 n3 = *(const f16x8*)(wn + 1536);
      #pragma unroll
      for (int s = 0; s < S; ++s) {
        f16x8 a = *(const f16x8*)(a_base + s * 16 * IPITCH + ks * 32);
        acc[0][s] = MFMA16(b0, a, acc[0][s]);
        acc[1][s] = MFMA16(b1, a, acc[1][s]);
        acc[2][s] = MFMA16(b2, a, acc[2][s]);
        acc[3][s] = MFMA16(b3, a, acc[3][s]);
      }
      b0 = n0; b1 = n1; b2 = n2; b3 = n3;
    }
    #pragma unroll
    for (int s = 0; s < S; ++s) {
      f16x8 a = *(const f16x8*)(a_base + s * 16 * IPITCH + (KS - 1) * 32);
      acc[0][s] = MFMA16(b0, a, acc[0][s]);
      acc[1][s] = MFMA16(b1, a, acc[1][s]);
      acc[2][s] = MFMA16(b2, a, acc[2][s]);
      acc[3][s] = MFMA16(b3, a, acc[3][s]);
    }

    // epilogue: per s, this lane owns batch row m and 4 consecutive features
    const int nb = t * 16 + lg * 4;
    #pragma unroll
    for (int s = 0; s < S; ++s) {
      const int m = mbase + s * 16 + l15;
      float o[4];
      #pragma unroll
      for (int q = 0; q < 4; ++q) {
        float th1 = ftanh(acc[0][s][q]);
        float th2 = ftanh(acc[1][s][q]);
        float ti  = fsigm(acc[3][s][q] - acc[2][s][q]);
        o[q] = th1 + ti * (th2 - th1);
      }
      if (LAST) {
        float4 v = make_float4(o[0], o[1], o[2], o[3]);
        *(float4*)(out_g + m * 64 + nb) = v;       // contiguous 4KB per wave
      } else if (nb + 4 <= HID) {
        f16x4 h = {(_Float16)o[0], (_Float16)o[1], (_Float16)o[2], (_Float16)o[3]};
        *(f16x4*)(out_lds + m * OPITCH + nb) = h;  // one b64 write
      } else {
        #pragma unroll
        for (int q = 0; q < 4; ++q)
          if (nb + q < HID) out_lds[m * OPITCH + nb + q] = (_Float16)o[q];
      }
    }
  }
}

__global__ __launch_bounds__(512, 4) void cfc_fused(
    const float* __restrict__ x,
    const _Float16* __restrict__ wt0, const _Float16* __restrict__ wt1,
    const _Float16* __restrict__ wt2,
    float* __restrict__ out)
{
  __shared__ __align__(16) _Float16 xs [BM * PX];   // 13312 B
  __shared__ __align__(16) _Float16 h0s[BM * PH0];  // 37888 B
  __shared__ __align__(16) _Float16 h1s[BM * PH1];  // 25600 B  -> 76800 total
  const int tid  = threadIdx.x;
  const int lane = tid & 63;
  const int wid  = tid >> 6;
  const int m0 = blockIdx.x * BM;

  // pad columns: 1.0 at the bias slot k==IN, 0 elsewhere in [IN, KP)
  for (int i = tid; i < BM * 22; i += 512) { int r = i / 22, c = IN0 + i - r * 22; xs [r * PX  + c] = (_Float16)(c == IN0 ? 1.f : 0.f); }
  for (int i = tid; i < BM * 19; i += 512) { int r = i / 19, c = H0  + i - r * 19; h0s[r * PH0 + c] = (_Float16)(c == H0  ? 1.f : 0.f); }
  for (int i = tid; i < BM * 13; i += 512) { int r = i / 13, c = H1  + i - r * 13; h1s[r * PH1 + c] = (_Float16)(c == H1  ? 1.f : 0.f); }

  // stage x (fp32 -> fp16) into LDS, float2 loads, packed b32 LDS writes
  for (int i = tid; i < BM * 37; i += 512) {
    int r = i / 37, p = i - r * 37;
    float2 v = ((const float2*)x)[(size_t)(m0 + r) * 37 + p];
    f16x2 hv = {(_Float16)v.x, (_Float16)v.y};
    *(f16x2*)(xs + r * PX + 2 * p) = hv;
  }
  __syncthreads();

  layer_run<KS0, NP0, H0, PX,  PH0, false, 4, 1>(xs,  h0s, nullptr, wt0, lane, wid);
  __syncthreads();
  layer_run<KS1, NP1, H1, PH0, PH1, false, 4, 1>(h0s, h1s, nullptr, wt1, lane, wid);
  __syncthreads();
  layer_run<KS2, NP2, H2, PH1, 1,   true,  2, 2>(h1s, nullptr, out + (size_t)m0 * 64,
                                                 wt2, lane, wid);
}

// Pack weights into fragment-major order. One thread per (chunk, lane):
// wt[idx*8 + j] = W_m[k][n] for k = ks*32+(lane>>4)*8+j, n = t*16+(lane&15),
// masked for ff mats; row k==IN carries the bias vector; zero elsewhere.
__global__ void pack_w(const float* __restrict__ wf1, const float* __restrict__ wf2,
                       const float* __restrict__ wta, const float* __restrict__ wtb,
                       const float* __restrict__ bf1, const float* __restrict__ bf2,
                       const float* __restrict__ bta, const float* __restrict__ btb,
                       const int* __restrict__ mask, _Float16* __restrict__ wt,
                       int IN, int HID, int KS, int NT)
{
  int idx = blockIdx.x * 256 + threadIdx.x;
  int total = NT * KS * 4 * 64;
  if (idx >= total) return;
  int lane = idx & 63;
  int c = idx >> 6;          // chunk = (t*KS + ks)*4 + m
  int m = c & 3;
  int tk = c >> 2;
  int ks = tk % KS;
  int t  = tk / KS;
  int n  = t * 16 + (lane & 15);
  int k0 = ks * 32 + (lane >> 4) * 8;
  const float* w = (m == 0) ? wf1 : (m == 1) ? wf2 : (m == 2) ? wta : wtb;
  const float* b = (m == 0) ? bf1 : (m == 1) ? bf2 : (m == 2) ? bta : btb;
  f16x8 v = {};
  if (n < HID) {
    #pragma unroll
    for (int j = 0; j < 8; ++j) {
      int k = k0 + j;
      float f = 0.f;
      if (k < IN) {
        f = w[k * HID + n];
        if (m < 2) f *= (float)mask[k * HID + n];
      } else if (k == IN) {
        f = b[n];
      }
      v[j] = (_Float16)f;
    }
  }
  *(f16x8*)(wt + (size_t)idx * 8) = v;
}

extern "C" void kernel_launch(void* const* d_in, const int* in_sizes, int n_in,
                              void* d_out, int out_size, void* d_ws, size_t ws_size,
                              hipStream_t stream)
{
  const float* x = (const float*)d_in[0];
  const float* Wf1_0 = (const float*)d_in[1];
  const float* bf1_0 = (const float*)d_in[2];
  const float* Wf2_0 = (const float*)d_in[3];
  const float* bf2_0 = (const float*)d_in[4];
  const float* Wta_0 = (const float*)d_in[5];
  const float* bta_0 = (const float*)d_in[6];
  const float* Wtb_0 = (const float*)d_in[7];
  const float* btb_0 = (const float*)d_in[8];
  const int*   msk_0 = (const int*)  d_in[9];
  const float* Wf1_1 = (const float*)d_in[10];
  const float* bf1_1 = (const float*)d_in[11];
  const float* Wf2_1 = (const float*)d_in[12];
  const float* bf2_1 = (const float*)d_in[13];
  const float* Wta_1 = (const float*)d_in[14];
  const float* bta_1 = (const float*)d_in[15];
  const float* Wtb_1 = (const float*)d_in[16];
  const float* btb_1 = (const float*)d_in[17];
  const int*   msk_1 = (const int*)  d_in[18];
  const float* Wf1_2 = (const float*)d_in[19];
  const float* bf1_2 = (const float*)d_in[20];
  const float* Wf2_2 = (const float*)d_in[21];
  const float* bf2_2 = (const float*)d_in[22];
  const float* Wta_2 = (const float*)d_in[23];
  const float* bta_2 = (const float*)d_in[24];
  const float* Wtb_2 = (const float*)d_in[25];
  const float* btb_2 = (const float*)d_in[26];
  const int*   msk_2 = (const int*)  d_in[27];

  char* ws = (char*)d_ws;
  _Float16* wt0 = (_Float16*)(ws + 0);        // 17*3*4*1024 = 208896
  _Float16* wt1 = (_Float16*)(ws + 208896);   // 12*9*4*1024 = 442368
  _Float16* wt2 = (_Float16*)(ws + 651264);   //  4*6*4*1024 =  98304

  pack_w<<<(17 * KS0 * 4 * 64 + 255) / 256, 256, 0, stream>>>(
      Wf1_0, Wf2_0, Wta_0, Wtb_0, bf1_0, bf2_0, bta_0, btb_0, msk_0, wt0, IN0, H0, KS0, 17);
  pack_w<<<(12 * KS1 * 4 * 64 + 255) / 256, 256, 0, stream>>>(
      Wf1_1, Wf2_1, Wta_1, Wtb_1, bf1_1, bf2_1, bta_1, btb_1, msk_1, wt1, H0, H1, KS1, 12);
  pack_w<<<( 4 * KS2 * 4 * 64 + 255) / 256, 256, 0, stream>>>(
      Wf1_2, Wf2_2, Wta_2, Wtb_2, bf1_2, bf2_2, bta_2, btb_2, msk_2, wt2, H1, H2, KS2, 4);

  cfc_fused<<<65536 / BM, 512, 0, stream>>>(x, wt0, wt1, wt2, (float*)d_out);
}

// Round 10
// 82.671 us; speedup vs baseline: 3.5863x; 1.0091x over previous
//
#include <hip/hip_runtime.h>
#include <hip/hip_fp16.h>

typedef _Float16 f16x8 __attribute__((ext_vector_type(8)));
typedef _Float16 f16x4 __attribute__((ext_vector_type(4)));
typedef _Float16 f16x2 __attribute__((ext_vector_type(2)));
typedef float    f32x4 __attribute__((ext_vector_type(4)));

#define BM 64     // 64-row block tile -> 76.8 KB LDS -> 2 blocks/CU

// layer geometry (h=0 => only first IN rows of each weight matter; the
// padded K range includes a bias row at k==IN carrying 1.0 in activations)
#define IN0 74
#define H0  269
#define H1  179
#define H2  64
#define KS0 3     // ceil((IN0+1)/32)
#define KS1 9     // ceil((H0+1)/32)
#define KS2 6     // ceil((H1+1)/32)
#define NP0 272
#define NP1 192
#define NP2 64
#define PX  104   // LDS row pitches (halfs): odd multiples of 16B -> spread banks
#define PH0 296
#define PH1 200

// SWAPPED operands: weights as the A-matrix, activations as B.
// A/B fragment layouts are symmetric (lane&15 = row/col, (lane>>4)*8+j = k),
// so the SAME packed weight frag and the SAME LDS activation read work; the
// C/D layout becomes col(lane&15)=batch row, row(lg*4+q)=feature -> each
// lane's 4 outputs are 4 CONSECUTIVE features of one batch row.
#define MFMA16(a, b, c) __builtin_amdgcn_mfma_f32_16x16x32_f16(a, b, c, 0, 0, 0)

__device__ __forceinline__ float fsigm(float z) {
  return __builtin_amdgcn_rcpf(1.f + __expf(-z));
}
__device__ __forceinline__ float ftanh(float v) {
  return 1.f - 2.f * __builtin_amdgcn_rcpf(1.f + __expf(2.f * v));
}

// One CfC layer for this block's 64 rows. 8 waves iterate flat work-units
// u = (tile t = u/G, row-group u%G of S*16 rows). Per unit ONE K-sweep with
// all 4 matrices accumulating (acc[4][S] in AGPRs): 1 LDS A-read feeds 4
// MFMAs. NO register prefetch window: b[4] is loaded just-in-time at the
// top of a FORCIBLY ROLLED (#pragma unroll 1) ks loop — the ~250cy L2
// latency is hidden by the other 3 waves/SIMD (TLP), not ILP. This is the
// first structure whose live set (acc 64 AGPR + ~54 arch) truly fits the
// 64-arch/64-AGPR split that __launch_bounds__(512,4) imposes.
// Epilogue computes o = th1 + sigmoid(tb-ta)*(th2-th1) inline and writes
// packed: f16x4 b64 to LDS (or float4 to global for the last layer).
// Bias arrives via the k==IN one-hot activation column.
template<int KS, int NP, int HID, int IPITCH, int OPITCH, bool LAST, int S, int G>
__device__ __forceinline__ void layer_run(
    const _Float16* in_lds, _Float16* out_lds, float* out_g,
    const _Float16* __restrict__ wt, int lane, int wid)
{
  constexpr int NT = NP / 16;
  const int l15 = lane & 15;
  const int lg  = lane >> 4;
  #pragma unroll 1
  for (int u = wid; u < NT * G; u += 8) {
    const int t     = u / G;
    const int mbase = (u % G) * (S * 16);
    const _Float16* a_base = in_lds + (mbase + l15) * IPITCH + lg * 8;
    const _Float16* wtt = wt + (size_t)(t * KS * 4) * 512 + lane * 8;

    f32x4 acc[4][S] = {};
    #pragma unroll 1
    for (int ks = 0; ks < KS; ++ks) {
      const _Float16* wk = wtt + (size_t)ks * 2048;
      f16x8 b0 = *(const f16x8*)(wk);
      f16x8 b1 = *(const f16x8*)(wk + 512);
      f16x8 b2 = *(const f16x8*)(wk + 1024);
      f16x8 b3 = *(const f16x8*)(wk + 1536);
      #pragma unroll
      for (int s = 0; s < S; ++s) {
        f16x8 a = *(const f16x8*)(a_base + s * 16 * IPITCH + ks * 32);
        acc[0][s] = MFMA16(b0, a, acc[0][s]);
        acc[1][s] = MFMA16(b1, a, acc[1][s]);
        acc[2][s] = MFMA16(b2, a, acc[2][s]);
        acc[3][s] = MFMA16(b3, a, acc[3][s]);
      }
    }

    // epilogue: per s, this lane owns batch row m and 4 consecutive features
    const int nb = t * 16 + lg * 4;
    #pragma unroll
    for (int s = 0; s < S; ++s) {
      const int m = mbase + s * 16 + l15;
      float o[4];
      #pragma unroll
      for (int q = 0; q < 4; ++q) {
        float th1 = ftanh(acc[0][s][q]);
        float th2 = ftanh(acc[1][s][q]);
        float ti  = fsigm(acc[3][s][q] - acc[2][s][q]);
        o[q] = th1 + ti * (th2 - th1);
      }
      if (LAST) {
        float4 v = make_float4(o[0], o[1], o[2], o[3]);
        *(float4*)(out_g + m * 64 + nb) = v;       // contiguous 4KB per wave
      } else if (nb + 4 <= HID) {
        f16x4 h = {(_Float16)o[0], (_Float16)o[1], (_Float16)o[2], (_Float16)o[3]};
        *(f16x4*)(out_lds + m * OPITCH + nb) = h;  // one b64 write
      } else {
        #pragma unroll
        for (int q = 0; q < 4; ++q)
          if (nb + q < HID) out_lds[m * OPITCH + nb + q] = (_Float16)o[q];
      }
    }
  }
}

__global__ __launch_bounds__(512, 4) void cfc_fused(
    const float* __restrict__ x,
    const _Float16* __restrict__ wt0, const _Float16* __restrict__ wt1,
    const _Float16* __restrict__ wt2,
    float* __restrict__ out)
{
  __shared__ __align__(16) _Float16 xs [BM * PX];   // 13312 B
  __shared__ __align__(16) _Float16 h0s[BM * PH0];  // 37888 B
  __shared__ __align__(16) _Float16 h1s[BM * PH1];  // 25600 B  -> 76800 total
  const int tid  = threadIdx.x;
  const int lane = tid & 63;
  const int wid  = tid >> 6;
  const int m0 = blockIdx.x * BM;

  // pad columns: 1.0 at the bias slot k==IN, 0 elsewhere in [IN, KP)
  for (int i = tid; i < BM * 22; i += 512) { int r = i / 22, c = IN0 + i - r * 22; xs [r * PX  + c] = (_Float16)(c == IN0 ? 1.f : 0.f); }
  for (int i = tid; i < BM * 19; i += 512) { int r = i / 19, c = H0  + i - r * 19; h0s[r * PH0 + c] = (_Float16)(c == H0  ? 1.f : 0.f); }
  for (int i = tid; i < BM * 13; i += 512) { int r = i / 13, c = H1  + i - r * 13; h1s[r * PH1 + c] = (_Float16)(c == H1  ? 1.f : 0.f); }

  // stage x (fp32 -> fp16) into LDS, float2 loads, packed b32 LDS writes
  for (int i = tid; i < BM * 37; i += 512) {
    int r = i / 37, p = i - r * 37;
    float2 v = ((const float2*)x)[(size_t)(m0 + r) * 37 + p];
    f16x2 hv = {(_Float16)v.x, (_Float16)v.y};
    *(f16x2*)(xs + r * PX + 2 * p) = hv;
  }
  __syncthreads();

  layer_run<KS0, NP0, H0, PX,  PH0, false, 4, 1>(xs,  h0s, nullptr, wt0, lane, wid);
  __syncthreads();
  layer_run<KS1, NP1, H1, PH0, PH1, false, 4, 1>(h0s, h1s, nullptr, wt1, lane, wid);
  __syncthreads();
  layer_run<KS2, NP2, H2, PH1, 1,   true,  2, 2>(h1s, nullptr, out + (size_t)m0 * 64,
                                                 wt2, lane, wid);
}

// Pack weights into fragment-major order. One thread per (chunk, lane):
// wt[idx*8 + j] = W_m[k][n] for k = ks*32+(lane>>4)*8+j, n = t*16+(lane&15),
// masked for ff mats; row k==IN carries the bias vector; zero elsewhere.
__global__ void pack_w(const float* __restrict__ wf1, const float* __restrict__ wf2,
                       const float* __restrict__ wta, const float* __restrict__ wtb,
                       const float* __restrict__ bf1, const float* __restrict__ bf2,
                       const float* __restrict__ bta, const float* __restrict__ btb,
                       const int* __restrict__ mask, _Float16* __restrict__ wt,
                       int IN, int HID, int KS, int NT)
{
  int idx = blockIdx.x * 256 + threadIdx.x;
  int total = NT * KS * 4 * 64;
  if (idx >= total) return;
  int lane = idx & 63;
  int c = idx >> 6;          // chunk = (t*KS + ks)*4 + m
  int m = c & 3;
  int tk = c >> 2;
  int ks = tk % KS;
  int t  = tk / KS;
  int n  = t * 16 + (lane & 15);
  int k0 = ks * 32 + (lane >> 4) * 8;
  const float* w = (m == 0) ? wf1 : (m == 1) ? wf2 : (m == 2) ? wta : wtb;
  const float* b = (m == 0) ? bf1 : (m == 1) ? bf2 : (m == 2) ? bta : btb;
  f16x8 v = {};
  if (n < HID) {
    #pragma unroll
    for (int j = 0; j < 8; ++j) {
      int k = k0 + j;
      float f = 0.f;
      if (k < IN) {
        f = w[k * HID + n];
        if (m < 2) f *= (float)mask[k * HID + n];
      } else if (k == IN) {
        f = b[n];
      }
      v[j] = (_Float16)f;
    }
  }
  *(f16x8*)(wt + (size_t)idx * 8) = v;
}

extern "C" void kernel_launch(void* const* d_in, const int* in_sizes, int n_in,
                              void* d_out, int out_size, void* d_ws, size_t ws_size,
                              hipStream_t stream)
{
  const float* x = (const float*)d_in[0];
  const float* Wf1_0 = (const float*)d_in[1];
  const float* bf1_0 = (const float*)d_in[2];
  const float* Wf2_0 = (const float*)d_in[3];
  const float* bf2_0 = (const float*)d_in[4];
  const float* Wta_0 = (const float*)d_in[5];
  const float* bta_0 = (const float*)d_in[6];
  const float* Wtb_0 = (const float*)d_in[7];
  const float* btb_0 = (const float*)d_in[8];
  const int*   msk_0 = (const int*)  d_in[9];
  const float* Wf1_1 = (const float*)d_in[10];
  const float* bf1_1 = (const float*)d_in[11];
  const float* Wf2_1 = (const float*)d_in[12];
  const float* bf2_1 = (const float*)d_in[13];
  const float* Wta_1 = (const float*)d_in[14];
  const float* bta_1 = (const float*)d_in[15];
  const float* Wtb_1 = (const float*)d_in[16];
  const float* btb_1 = (const float*)d_in[17];
  const int*   msk_1 = (const int*)  d_in[18];
  const float* Wf1_2 = (const float*)d_in[19];
  const float* bf1_2 = (const float*)d_in[20];
  const float* Wf2_2 = (const float*)d_in[21];
  const float* bf2_2 = (const float*)d_in[22];
  const float* Wta_2 = (const float*)d_in[23];
  const float* bta_2 = (const float*)d_in[24];
  const float* Wtb_2 = (const float*)d_in[25];
  const float* btb_2 = (const float*)d_in[26];
  const int*   msk_2 = (const int*)  d_in[27];

  char* ws = (char*)d_ws;
  _Float16* wt0 = (_Float16*)(ws + 0);        // 17*3*4*1024 = 208896
  _Float16* wt1 = (_Float16*)(ws + 208896);   // 12*9*4*1024 = 442368
  _Float16* wt2 = (_Float16*)(ws + 651264);   //  4*6*4*1024 =  98304

  pack_w<<<(17 * KS0 * 4 * 64 + 255) / 256, 256, 0, stream>>>(
      Wf1_0, Wf2_0, Wta_0, Wtb_0, bf1_0, bf2_0, bta_0, btb_0, msk_0, wt0, IN0, H0, KS0, 17);
  pack_w<<<(12 * KS1 * 4 * 64 + 255) / 256, 256, 0, stream>>>(
      Wf1_1, Wf2_1, Wta_1, Wtb_1, bf1_1, bf2_1, bta_1, btb_1, msk_1, wt1, H0, H1, KS1, 12);
  pack_w<<<( 4 * KS2 * 4 * 64 + 255) / 256, 256, 0, stream>>>(
      Wf1_2, Wf2_2, Wta_2, Wtb_2, bf1_2, bf2_2, bta_2, btb_2, msk_2, wt2, H1, H2, KS2, 4);

  cfc_fused<<<65536 / BM, 512, 0, stream>>>(x, wt0, wt1, wt2, (float*)d_out);
}

// Round 11
// 80.648 us; speedup vs baseline: 3.6763x; 1.0251x over previous
//
#include <hip/hip_runtime.h>
#include <hip/hip_fp16.h>

typedef _Float16 f16x8 __attribute__((ext_vector_type(8)));
typedef _Float16 f16x4 __attribute__((ext_vector_type(4)));
typedef _Float16 f16x2 __attribute__((ext_vector_type(2)));
typedef float    f32x4 __attribute__((ext_vector_type(4)));

#define BM 64     // 64-row block tile -> 76.8 KB LDS -> 2 blocks/CU

// layer geometry (h=0 => only first IN rows of each weight matter; the
// padded K range includes a bias row at k==IN carrying 1.0 in activations)
#define IN0 74
#define H0  269
#define H1  179
#define H2  64
#define KS0 3     // ceil((IN0+1)/32)
#define KS1 9     // ceil((H0+1)/32)
#define KS2 6     // ceil((H1+1)/32)
#define NP0 272
#define NP1 192
#define NP2 64
#define PX  104   // LDS row pitches (halfs): odd multiples of 16B -> spread banks
#define PH0 296
#define PH1 200

// SWAPPED operands: weights as the A-matrix, activations as B.
// C/D layout: col(lane&15)=batch row, row(lg*4+q)=feature -> each lane's 4
// outputs are 4 CONSECUTIVE features of one batch row.
#define MFMA16(a, b, c) __builtin_amdgcn_mfma_f32_16x16x32_f16(a, b, c, 0, 0, 0)

// ff weights/biases are pre-scaled by 2 at pack time, so acc0 = 2*f1 and
// tanh(f1) = 1 - 2*r1 with r1 = 1/(1+exp(acc0)). Gate combine in r-space:
// o = th1 + ti*(th2-th1) = 1 - 2*(r1 - ti*(r1-r2)).
__device__ __forceinline__ float rform(float y) {
  return __builtin_amdgcn_rcpf(1.f + __expf(y));
}

// Anti-lockstep stagger: all waves leave each barrier the same cycle and run
// identical-length phases -> sweep(MFMA) and epilogue(VALU) never overlap
// across waves. Sleep wave (wid | blockparity<<3) * ~128 cyc to spread wave
// phases over ~2k cyc of the ~4.5k-cyc unit rhythm (m114: MFMA-wave and
// VALU-wave co-schedule fully once dephased).
__device__ __forceinline__ void stagger(int d) {
  if (d & 1) __builtin_amdgcn_s_sleep(2);
  if (d & 2) __builtin_amdgcn_s_sleep(4);
  if (d & 4) __builtin_amdgcn_s_sleep(8);
  if (d & 8) __builtin_amdgcn_s_sleep(16);
}

// One CfC layer for this block's 64 rows. 8 waves iterate flat work-units
// u = (tile t = u/G, row-group u%G of S*16 rows). Per unit ONE K-sweep with
// all 4 matrices accumulating (acc[4][S] in AGPRs): 1 LDS A-read feeds 4
// MFMAs. b[4] loaded just-in-time in a FORCIBLY ROLLED (#pragma unroll 1)
// ks loop (fits the 64-arch/64-AGPR split of __launch_bounds__(512,4);
// TLP across staggered waves hides the L2 latency).
template<int KS, int NP, int HID, int IPITCH, int OPITCH, bool LAST, int S, int G>
__device__ __forceinline__ void layer_run(
    const _Float16* in_lds, _Float16* out_lds, float* out_g,
    const _Float16* __restrict__ wt, int lane, int wid)
{
  constexpr int NT = NP / 16;
  const int l15 = lane & 15;
  const int lg  = lane >> 4;
  #pragma unroll 1
  for (int u = wid; u < NT * G; u += 8) {
    const int t     = u / G;
    const int mbase = (u % G) * (S * 16);
    const _Float16* a_base = in_lds + (mbase + l15) * IPITCH + lg * 8;
    const _Float16* wtt = wt + (size_t)(t * KS * 4) * 512 + lane * 8;

    f32x4 acc[4][S] = {};
    #pragma unroll 1
    for (int ks = 0; ks < KS; ++ks) {
      const _Float16* wk = wtt + (size_t)ks * 2048;
      f16x8 b0 = *(const f16x8*)(wk);
      f16x8 b1 = *(const f16x8*)(wk + 512);
      f16x8 b2 = *(const f16x8*)(wk + 1024);
      f16x8 b3 = *(const f16x8*)(wk + 1536);
      #pragma unroll
      for (int s = 0; s < S; ++s) {
        f16x8 a = *(const f16x8*)(a_base + s * 16 * IPITCH + ks * 32);
        acc[0][s] = MFMA16(b0, a, acc[0][s]);
        acc[1][s] = MFMA16(b1, a, acc[1][s]);
        acc[2][s] = MFMA16(b2, a, acc[2][s]);
        acc[3][s] = MFMA16(b3, a, acc[3][s]);
      }
    }

    // epilogue: per s, this lane owns batch row m and 4 consecutive features
    const int nb = t * 16 + lg * 4;
    #pragma unroll
    for (int s = 0; s < S; ++s) {
      const int m = mbase + s * 16 + l15;
      float o[4];
      #pragma unroll
      for (int q = 0; q < 4; ++q) {
        float r1 = rform(acc[0][s][q]);                  // acc0 = 2*f1
        float r2 = rform(acc[1][s][q]);                  // acc1 = 2*f2
        float ti = rform(acc[2][s][q] - acc[3][s][q]);   // sigmoid(tb-ta)
        o[q] = 1.f - 2.f * (r1 - ti * (r1 - r2));
      }
      if (LAST) {
        float4 v = make_float4(o[0], o[1], o[2], o[3]);
        *(float4*)(out_g + m * 64 + nb) = v;       // contiguous 4KB per wave
      } else if (nb + 4 <= HID) {
        f16x4 h = {(_Float16)o[0], (_Float16)o[1], (_Float16)o[2], (_Float16)o[3]};
        *(f16x4*)(out_lds + m * OPITCH + nb) = h;  // one b64 write
      } else {
        #pragma unroll
        for (int q = 0; q < 4; ++q)
          if (nb + q < HID) out_lds[m * OPITCH + nb + q] = (_Float16)o[q];
      }
    }
  }
}

__global__ __launch_bounds__(512, 4) void cfc_fused(
    const float* __restrict__ x,
    const _Float16* __restrict__ wt0, const _Float16* __restrict__ wt1,
    const _Float16* __restrict__ wt2,
    float* __restrict__ out)
{
  __shared__ __align__(16) _Float16 xs [BM * PX];   // 13312 B
  __shared__ __align__(16) _Float16 h0s[BM * PH0];  // 37888 B
  __shared__ __align__(16) _Float16 h1s[BM * PH1];  // 25600 B  -> 76800 total
  const int tid  = threadIdx.x;
  const int lane = tid & 63;
  const int wid  = tid >> 6;
  const int m0 = blockIdx.x * BM;
  const int sd = wid | ((blockIdx.x & 1) << 3);

  // pad columns: 1.0 at the bias slot k==IN, 0 elsewhere in [IN, KP)
  for (int i = tid; i < BM * 22; i += 512) { int r = i / 22, c = IN0 + i - r * 22; xs [r * PX  + c] = (_Float16)(c == IN0 ? 1.f : 0.f); }
  for (int i = tid; i < BM * 19; i += 512) { int r = i / 19, c = H0  + i - r * 19; h0s[r * PH0 + c] = (_Float16)(c == H0  ? 1.f : 0.f); }
  for (int i = tid; i < BM * 13; i += 512) { int r = i / 13, c = H1  + i - r * 13; h1s[r * PH1 + c] = (_Float16)(c == H1  ? 1.f : 0.f); }

  // stage x (fp32 -> fp16) into LDS, float2 loads, packed b32 LDS writes
  for (int i = tid; i < BM * 37; i += 512) {
    int r = i / 37, p = i - r * 37;
    float2 v = ((const float2*)x)[(size_t)(m0 + r) * 37 + p];
    f16x2 hv = {(_Float16)v.x, (_Float16)v.y};
    *(f16x2*)(xs + r * PX + 2 * p) = hv;
  }
  __syncthreads();
  stagger(sd);
  layer_run<KS0, NP0, H0, PX,  PH0, false, 4, 1>(xs,  h0s, nullptr, wt0, lane, wid);
  __syncthreads();
  stagger(sd);
  layer_run<KS1, NP1, H1, PH0, PH1, false, 4, 1>(h0s, h1s, nullptr, wt1, lane, wid);
  __syncthreads();
  stagger(sd);
  layer_run<KS2, NP2, H2, PH1, 1,   true,  2, 2>(h1s, nullptr, out + (size_t)m0 * 64,
                                                 wt2, lane, wid);
}

// Pack weights into fragment-major order. One thread per (chunk, lane):
// wt[idx*8 + j] = W_m[k][n] for k = ks*32+(lane>>4)*8+j, n = t*16+(lane&15),
// masked for ff mats; row k==IN carries the bias vector; zero elsewhere.
// ff1/ff2 (m<2) weights+bias are PRE-SCALED by 2 so the kernel's tanh is
// 1-2/(1+exp(acc)) with no per-output doubling (exact in fp16: *2 = exp bump).
__global__ void pack_w(const float* __restrict__ wf1, const float* __restrict__ wf2,
                       const float* __restrict__ wta, const float* __restrict__ wtb,
                       const float* __restrict__ bf1, const float* __restrict__ bf2,
                       const float* __restrict__ bta, const float* __restrict__ btb,
                       const int* __restrict__ mask, _Float16* __restrict__ wt,
                       int IN, int HID, int KS, int NT)
{
  int idx = blockIdx.x * 256 + threadIdx.x;
  int total = NT * KS * 4 * 64;
  if (idx >= total) return;
  int lane = idx & 63;
  int c = idx >> 6;          // chunk = (t*KS + ks)*4 + m
  int m = c & 3;
  int tk = c >> 2;
  int ks = tk % KS;
  int t  = tk / KS;
  int n  = t * 16 + (lane & 15);
  int k0 = ks * 32 + (lane >> 4) * 8;
  const float* w = (m == 0) ? wf1 : (m == 1) ? wf2 : (m == 2) ? wta : wtb;
  const float* b = (m == 0) ? bf1 : (m == 1) ? bf2 : (m == 2) ? bta : btb;
  f16x8 v = {};
  if (n < HID) {
    #pragma unroll
    for (int j = 0; j < 8; ++j) {
      int k = k0 + j;
      float f = 0.f;
      if (k < IN) {
        f = w[k * HID + n];
        if (m < 2) f *= (float)mask[k * HID + n];
      } else if (k == IN) {
        f = b[n];
      }
      if (m < 2) f *= 2.0f;
      v[j] = (_Float16)f;
    }
  }
  *(f16x8*)(wt + (size_t)idx * 8) = v;
}

extern "C" void kernel_launch(void* const* d_in, const int* in_sizes, int n_in,
                              void* d_out, int out_size, void* d_ws, size_t ws_size,
                              hipStream_t stream)
{
  const float* x = (const float*)d_in[0];
  const float* Wf1_0 = (const float*)d_in[1];
  const float* bf1_0 = (const float*)d_in[2];
  const float* Wf2_0 = (const float*)d_in[3];
  const float* bf2_0 = (const float*)d_in[4];
  const float* Wta_0 = (const float*)d_in[5];
  const float* bta_0 = (const float*)d_in[6];
  const float* Wtb_0 = (const float*)d_in[7];
  const float* btb_0 = (const float*)d_in[8];
  const int*   msk_0 = (const int*)  d_in[9];
  const float* Wf1_1 = (const float*)d_in[10];
  const float* bf1_1 = (const float*)d_in[11];
  const float* Wf2_1 = (const float*)d_in[12];
  const float* bf2_1 = (const float*)d_in[13];
  const float* Wta_1 = (const float*)d_in[14];
  const float* bta_1 = (const float*)d_in[15];
  const float* Wtb_1 = (const float*)d_in[16];
  const float* btb_1 = (const float*)d_in[17];
  const int*   msk_1 = (const int*)  d_in[18];
  const float* Wf1_2 = (const float*)d_in[19];
  const float* bf1_2 = (const float*)d_in[20];
  const float* Wf2_2 = (const float*)d_in[21];
  const float* bf2_2 = (const float*)d_in[22];
  const float* Wta_2 = (const float*)d_in[23];
  const float* bta_2 = (const float*)d_in[24];
  const float* Wtb_2 = (const float*)d_in[25];
  const float* btb_2 = (const float*)d_in[26];
  const int*   msk_2 = (const int*)  d_in[27];

  char* ws = (char*)d_ws;
  _Float16* wt0 = (_Float16*)(ws + 0);        // 17*3*4*1024 = 208896
  _Float16* wt1 = (_Float16*)(ws + 208896);   // 12*9*4*1024 = 442368
  _Float16* wt2 = (_Float16*)(ws + 651264);   //  4*6*4*1024 =  98304

  pack_w<<<(17 * KS0 * 4 * 64 + 255) / 256, 256, 0, stream>>>(
      Wf1_0, Wf2_0, Wta_0, Wtb_0, bf1_0, bf2_0, bta_0, btb_0, msk_0, wt0, IN0, H0, KS0, 17);
  pack_w<<<(12 * KS1 * 4 * 64 + 255) / 256, 256, 0, stream>>>(
      Wf1_1, Wf2_1, Wta_1, Wtb_1, bf1_1, bf2_1, bta_1, btb_1, msk_1, wt1, H0, H1, KS1, 12);
  pack_w<<<( 4 * KS2 * 4 * 64 + 255) / 256, 256, 0, stream>>>(
      Wf1_2, Wf2_2, Wta_2, Wtb_2, bf1_2, bf2_2, bta_2, btb_2, msk_2, wt2, H1, H2, KS2, 4);

  cfc_fused<<<65536 / BM, 512, 0, stream>>>(x, wt0, wt1, wt2, (float*)d_out);
}

// Round 12
// 72.561 us; speedup vs baseline: 4.0860x; 1.1115x over previous
//
#include <hip/hip_runtime.h>
#include <hip/hip_fp16.h>

typedef _Float16 f16x8 __attribute__((ext_vector_type(8)));
typedef _Float16 f16x4 __attribute__((ext_vector_type(4)));
typedef _Float16 f16x2 __attribute__((ext_vector_type(2)));
typedef float    f32x4 __attribute__((ext_vector_type(4)));

#define BM 64     // 64-row block tile -> 76.8 KB LDS -> 2 blocks/CU

// layer geometry (h=0 => only first IN rows of each weight matter; the
// padded K range includes a bias row at k==IN carrying 1.0 in activations)
#define IN0 74
#define H0  269
#define H1  179
#define H2  64
#define KS0 3     // ceil((IN0+1)/32)
#define KS1 9     // ceil((H0+1)/32)
#define KS2 6     // ceil((H1+1)/32)
#define NP0 272
#define NP1 192
#define NP2 64
#define PX  104   // LDS row pitches (halfs): odd multiples of 16B -> spread banks
#define PH0 296
#define PH1 200

// SWAPPED operands: weights as the A-matrix, activations as B.
// C/D layout: col(lane&15)=batch row, row(lg*4+q)=feature -> each lane's 4
// outputs are 4 CONSECUTIVE features of one batch row.
#define MFMA16(a, b, c) __builtin_amdgcn_mfma_f32_16x16x32_f16(a, b, c, 0, 0, 0)

// THREE matrices per layer (was 4): m0 = 2*mask*Wf1 (+2*bf1 bias row),
// m1 = 2*mask*Wf2 (+2*bf2), m2 = Wtb - Wta (+ btb - bta). The time gate
// t_interp = sigmoid(tb - ta) depends only on the DIFFERENCE, which is
// linear -> fold into one packed matrix at pack time. ff weights pre-scaled
// by 2 so tanh(f) = 1 - 2*r with r = 1/(1+exp(acc)).
__device__ __forceinline__ float rform(float y) {
  return __builtin_amdgcn_rcpf(1.f + __expf(y));
}

// One CfC layer for this block's 64 rows. 8 waves iterate flat work-units
// u = (tile t = u/G, row-group u%G of S*16 rows). Per unit ONE K-sweep with
// 3 matrices accumulating (acc[3][S] = 48 AGPRs): 1 LDS A-read feeds 3
// MFMAs. Rolling 1-ahead B prefetch (24 regs) inside a FORCIBLY ROLLED
// (#pragma unroll 1), loop-split ks loop — the 3-matrix live set (~124
// unified) fits the 128-reg/wave budget of __launch_bounds__(512,4), which
// the 4-matrix version could not.
// Epilogue: r1,r2 = rform(acc0/1), ti = rform(-acc2) = sigmoid(tb-ta),
// o = 1 - 2*(r1 - ti*(r1-r2)); packed f16x4 LDS write / float4 global.
template<int KS, int NP, int HID, int IPITCH, int OPITCH, bool LAST, int S, int G>
__device__ __forceinline__ void layer_run(
    const _Float16* in_lds, _Float16* out_lds, float* out_g,
    const _Float16* __restrict__ wt, int lane, int wid)
{
  constexpr int NT = NP / 16;
  const int l15 = lane & 15;
  const int lg  = lane >> 4;
  #pragma unroll 1
  for (int u = wid; u < NT * G; u += 8) {
    const int t     = u / G;
    const int mbase = (u % G) * (S * 16);
    const _Float16* a_base = in_lds + (mbase + l15) * IPITCH + lg * 8;
    const _Float16* wtt = wt + (size_t)(t * KS * 3) * 512 + lane * 8;

    f32x4 acc[3][S] = {};
    f16x8 b0 = *(const f16x8*)(wtt);
    f16x8 b1 = *(const f16x8*)(wtt + 512);
    f16x8 b2 = *(const f16x8*)(wtt + 1024);
    #pragma unroll 1
    for (int ks = 0; ks < KS - 1; ++ks) {
      const _Float16* wn = wtt + (size_t)(ks + 1) * 1536;
      f16x8 n0 = *(const f16x8*)(wn);
      f16x8 n1 = *(const f16x8*)(wn + 512);
      f16x8 n2 = *(const f16x8*)(wn + 1024);
      #pragma unroll
      for (int s = 0; s < S; ++s) {
        f16x8 a = *(const f16x8*)(a_base + s * 16 * IPITCH + ks * 32);
        acc[0][s] = MFMA16(b0, a, acc[0][s]);
        acc[1][s] = MFMA16(b1, a, acc[1][s]);
        acc[2][s] = MFMA16(b2, a, acc[2][s]);
      }
      b0 = n0; b1 = n1; b2 = n2;
    }
    #pragma unroll
    for (int s = 0; s < S; ++s) {
      f16x8 a = *(const f16x8*)(a_base + s * 16 * IPITCH + (KS - 1) * 32);
      acc[0][s] = MFMA16(b0, a, acc[0][s]);
      acc[1][s] = MFMA16(b1, a, acc[1][s]);
      acc[2][s] = MFMA16(b2, a, acc[2][s]);
    }

    // epilogue: per s, this lane owns batch row m and 4 consecutive features
    const int nb = t * 16 + lg * 4;
    #pragma unroll
    for (int s = 0; s < S; ++s) {
      const int m = mbase + s * 16 + l15;
      float o[4];
      #pragma unroll
      for (int q = 0; q < 4; ++q) {
        float r1 = rform(acc[0][s][q]);        // acc0 = 2*f1
        float r2 = rform(acc[1][s][q]);        // acc1 = 2*f2
        float ti = rform(-acc[2][s][q]);       // sigmoid(tb-ta)
        o[q] = 1.f - 2.f * (r1 - ti * (r1 - r2));
      }
      if (LAST) {
        float4 v = make_float4(o[0], o[1], o[2], o[3]);
        *(float4*)(out_g + m * 64 + nb) = v;       // contiguous 4KB per wave
      } else if (nb + 4 <= HID) {
        f16x4 h = {(_Float16)o[0], (_Float16)o[1], (_Float16)o[2], (_Float16)o[3]};
        *(f16x4*)(out_lds + m * OPITCH + nb) = h;  // one b64 write
      } else {
        #pragma unroll
        for (int q = 0; q < 4; ++q)
          if (nb + q < HID) out_lds[m * OPITCH + nb + q] = (_Float16)o[q];
      }
    }
  }
}

__global__ __launch_bounds__(512, 4) void cfc_fused(
    const float* __restrict__ x,
    const _Float16* __restrict__ wt0, const _Float16* __restrict__ wt1,
    const _Float16* __restrict__ wt2,
    float* __restrict__ out)
{
  __shared__ __align__(16) _Float16 xs [BM * PX];   // 13312 B
  __shared__ __align__(16) _Float16 h0s[BM * PH0];  // 37888 B
  __shared__ __align__(16) _Float16 h1s[BM * PH1];  // 25600 B  -> 76800 total
  const int tid  = threadIdx.x;
  const int lane = tid & 63;
  const int wid  = tid >> 6;
  const int m0 = blockIdx.x * BM;

  // pad columns: 1.0 at the bias slot k==IN, 0 elsewhere in [IN, KP)
  for (int i = tid; i < BM * 22; i += 512) { int r = i / 22, c = IN0 + i - r * 22; xs [r * PX  + c] = (_Float16)(c == IN0 ? 1.f : 0.f); }
  for (int i = tid; i < BM * 19; i += 512) { int r = i / 19, c = H0  + i - r * 19; h0s[r * PH0 + c] = (_Float16)(c == H0  ? 1.f : 0.f); }
  for (int i = tid; i < BM * 13; i += 512) { int r = i / 13, c = H1  + i - r * 13; h1s[r * PH1 + c] = (_Float16)(c == H1  ? 1.f : 0.f); }

  // stage x (fp32 -> fp16) into LDS, float2 loads, packed b32 LDS writes
  for (int i = tid; i < BM * 37; i += 512) {
    int r = i / 37, p = i - r * 37;
    float2 v = ((const float2*)x)[(size_t)(m0 + r) * 37 + p];
    f16x2 hv = {(_Float16)v.x, (_Float16)v.y};
    *(f16x2*)(xs + r * PX + 2 * p) = hv;
  }
  __syncthreads();

  layer_run<KS0, NP0, H0, PX,  PH0, false, 4, 1>(xs,  h0s, nullptr, wt0, lane, wid);
  __syncthreads();
  layer_run<KS1, NP1, H1, PH0, PH1, false, 4, 1>(h0s, h1s, nullptr, wt1, lane, wid);
  __syncthreads();
  layer_run<KS2, NP2, H2, PH1, 1,   true,  2, 2>(h1s, nullptr, out + (size_t)m0 * 64,
                                                 wt2, lane, wid);
}

// Pack weights into fragment-major order, 3 matrices per layer.
// One thread per (chunk, lane): chunk c = (t*KS + ks)*3 + m, halfs j:
// k = ks*32+(lane>>4)*8+j, n = t*16+(lane&15).
// m=0: 2*mask*Wf1 (bias row 2*bf1); m=1: 2*mask*Wf2 (2*bf2);
// m=2: Wtb - Wta (bias row btb - bta). Zero outside [0,IN] x [0,HID).
__global__ void pack_w(const float* __restrict__ wf1, const float* __restrict__ wf2,
                       const float* __restrict__ wta, const float* __restrict__ wtb,
                       const float* __restrict__ bf1, const float* __restrict__ bf2,
                       const float* __restrict__ bta, const float* __restrict__ btb,
                       const int* __restrict__ mask, _Float16* __restrict__ wt,
                       int IN, int HID, int KS, int NT)
{
  int idx = blockIdx.x * 256 + threadIdx.x;
  int total = NT * KS * 3 * 64;
  if (idx >= total) return;
  int lane = idx & 63;
  int c = idx >> 6;          // chunk = (t*KS + ks)*3 + m
  int m = c % 3;
  int tk = c / 3;
  int ks = tk % KS;
  int t  = tk / KS;
  int n  = t * 16 + (lane & 15);
  int k0 = ks * 32 + (lane >> 4) * 8;
  f16x8 v = {};
  if (n < HID) {
    #pragma unroll
    for (int j = 0; j < 8; ++j) {
      int k = k0 + j;
      float f = 0.f;
      if (k < IN) {
        if (m == 0)      f = 2.f * wf1[k * HID + n] * (float)mask[k * HID + n];
        else if (m == 1) f = 2.f * wf2[k * HID + n] * (float)mask[k * HID + n];
        else             f = wtb[k * HID + n] - wta[k * HID + n];
      } else if (k == IN) {
        if (m == 0)      f = 2.f * bf1[n];
        else if (m == 1) f = 2.f * bf2[n];
        else             f = btb[n] - bta[n];
      }
      v[j] = (_Float16)f;
    }
  }
  *(f16x8*)(wt + (size_t)idx * 8) = v;
}

extern "C" void kernel_launch(void* const* d_in, const int* in_sizes, int n_in,
                              void* d_out, int out_size, void* d_ws, size_t ws_size,
                              hipStream_t stream)
{
  const float* x = (const float*)d_in[0];
  const float* Wf1_0 = (const float*)d_in[1];
  const float* bf1_0 = (const float*)d_in[2];
  const float* Wf2_0 = (const float*)d_in[3];
  const float* bf2_0 = (const float*)d_in[4];
  const float* Wta_0 = (const float*)d_in[5];
  const float* bta_0 = (const float*)d_in[6];
  const float* Wtb_0 = (const float*)d_in[7];
  const float* btb_0 = (const float*)d_in[8];
  const int*   msk_0 = (const int*)  d_in[9];
  const float* Wf1_1 = (const float*)d_in[10];
  const float* bf1_1 = (const float*)d_in[11];
  const float* Wf2_1 = (const float*)d_in[12];
  const float* bf2_1 = (const float*)d_in[13];
  const float* Wta_1 = (const float*)d_in[14];
  const float* bta_1 = (const float*)d_in[15];
  const float* Wtb_1 = (const float*)d_in[16];
  const float* btb_1 = (const float*)d_in[17];
  const int*   msk_1 = (const int*)  d_in[18];
  const float* Wf1_2 = (const float*)d_in[19];
  const float* bf1_2 = (const float*)d_in[20];
  const float* Wf2_2 = (const float*)d_in[21];
  const float* bf2_2 = (const float*)d_in[22];
  const float* Wta_2 = (const float*)d_in[23];
  const float* bta_2 = (const float*)d_in[24];
  const float* Wtb_2 = (const float*)d_in[25];
  const float* btb_2 = (const float*)d_in[26];
  const int*   msk_2 = (const int*)  d_in[27];

  char* ws = (char*)d_ws;
  _Float16* wt0 = (_Float16*)(ws + 0);        // 17*3*3*1024 = 156672
  _Float16* wt1 = (_Float16*)(ws + 156672);   // 12*9*3*1024 = 331776
  _Float16* wt2 = (_Float16*)(ws + 488448);   //  4*6*3*1024 =  73728

  pack_w<<<(17 * KS0 * 3 * 64 + 255) / 256, 256, 0, stream>>>(
      Wf1_0, Wf2_0, Wta_0, Wtb_0, bf1_0, bf2_0, bta_0, btb_0, msk_0, wt0, IN0, H0, KS0, 17);
  pack_w<<<(12 * KS1 * 3 * 64 + 255) / 256, 256, 0, stream>>>(
      Wf1_1, Wf2_1, Wta_1, Wtb_1, bf1_1, bf2_1, bta_1, btb_1, msk_1, wt1, H0, H1, KS1, 12);
  pack_w<<<( 4 * KS2 * 3 * 64 + 255) / 256, 256, 0, stream>>>(
      Wf1_2, Wf2_2, Wta_2, Wtb_2, bf1_2, bf2_2, bta_2, btb_2, msk_2, wt2, H1, H2, KS2, 4);

  cfc_fused<<<65536 / BM, 512, 0, stream>>>(x, wt0, wt1, wt2, (float*)d_out);
}